// Round 1
// 398.549 us; speedup vs baseline: 1.2846x; 1.2846x over previous
//
#include <hip/hip_runtime.h>

typedef float v4f __attribute__((ext_vector_type(4)));
typedef short v8s __attribute__((ext_vector_type(8)));

// round-to-nearest-even fp32 -> bf16
__device__ __forceinline__ unsigned short f2bf_rn(float f) {
  unsigned u = __float_as_uint(f);
  return (unsigned short)((u + 0x7fffu + ((u >> 16) & 1u)) >> 16);
}
__device__ __forceinline__ float bf2f(unsigned short h) {
  return __uint_as_float((unsigned)h << 16);
}

// tanh-approx gelu (JAX default) scaled by 1/PHI_C
__device__ __forceinline__ float gelu_phi(float x) {
  float t = tanhf(0.7978845608f * (x + 0.044715f * x * x * x));
  return 0.5f * x * (1.0f + t) * 1.5338375f;
}

// ---------------- MLP + input prep ----------------
__global__ __launch_bounds__(256) void k_mlp1(const float* __restrict__ emb, const float* __restrict__ W0,
                                              const float* __restrict__ x1, const float* __restrict__ x2,
                                              float* __restrict__ act1,
                                              unsigned short* __restrict__ s1c, unsigned short* __restrict__ v1c,
                                              unsigned short* __restrict__ s2c, unsigned short* __restrict__ v2c)
{
  const int blk = blockIdx.x, tid = threadIdx.x;
  if (blk < 128) {
    float s = 0.f;
#pragma unroll 8
    for (int xx = 0; xx < 64; ++xx) s += emb[blk * 64 + xx] * W0[xx * 256 + tid];
    act1[blk * 256 + tid] = gelu_phi(s * 0.125f);
  } else {
    // compact bf16 copies of s/v parts of x1 (blocks 128..135) and x2 (blocks 136..143)
    const int sel = (blk - 128) >> 3;
    const float* xs = sel ? x2 : x1;
    unsigned short* sc = sel ? s2c : s1c;
    unsigned short* vc = sel ? v2c : v1c;
    for (int i = ((blk - 128) & 7) * 256 + tid; i < 32768; i += 2048) {
      if (i < 8192) {
        sc[i] = f2bf_rn(xs[(i >> 6) * 256 + (i & 63)]);
      } else {
        const int t = i - 8192, g = t >> 13, r = t & 8191;
        vc[g * 8192 + r] = f2bf_rn(xs[(r >> 6) * 256 + 64 + (r & 63) * 3 + g]);
      }
    }
  }
}

__global__ __launch_bounds__(256) void k_mlp2(const float* __restrict__ act1, const float* __restrict__ W1,
                                              float* __restrict__ act2)
{
  const int b = blockIdx.x, j = threadIdx.x;
  float s = 0.f;
#pragma unroll 16
  for (int x = 0; x < 256; ++x) s += act1[b * 256 + x] * W1[x * 256 + j];
  act2[b * 256 + j] = gelu_phi(s * 0.0625f);
}

__global__ __launch_bounds__(256) void k_mlp3(const float* __restrict__ act2, const float* __restrict__ W2,
                                              float* __restrict__ hsT)
{
  const int o = blockIdx.x * 256 + threadIdx.x;
  const int b = o >> 6, e = o & 63;
  float s = 0.f;
#pragma unroll 16
  for (int x = 0; x < 256; ++x) s += act2[b * 256 + x] * W2[x * 64 + e];
  hsT[e * 128 + b] = gelu_phi(s * 0.0625f) * 0.125f;  // hs transposed [x][b]
}

// ---------------- fused tensor-product GEMM ----------------
// out-rows (M=1408) x K=(x,u,v)=262144 x N=w=64, A built in registers:
//   G0 (P0): rows b           : A = hs[x]*s1[u]*s2[v]
//   G1 (P1): rows 128+j*128+b : A = hs[x]*s1[u]*v2_j[v]
//   G2 (P2): rows 512+i*128+b : A = hs[x]*v1_i[u]*s2[v]
//   G3 (P3): rows 896+b       : A = hs[x]*sum_i v1_i[u]*v2_i[v]
//   G4 (P4): rows 1024+k*128+b: A = hs[x]*(v1_{k+1}[u]*v2_{k+2}[v] - v1_{k+2}[u]*v2_{k+1}[v])
// Each block: one (tensor, K-chunk); chunk = 2048 k's (csh=7) or 4096 (csh=6, two 2048 subs).
// Writes disjoint partial[chunk][row][w]; finalize sums chunks. No atomics, no zeroing needed.

template<int G>
__device__ __forceinline__ void gemm_body(
    const float* __restrict__ P,
    const unsigned short* __restrict__ f1g,   // s1c or v1c  [comp][128][64] bf16
    const unsigned short* __restrict__ f2g,   // s2c or v2c
    const float* __restrict__ hsT,            // [64][128] f32
    float* __restrict__ partial,
    int c, int csh,
    unsigned short* ldsF1, unsigned* ldsB32)
{
  constexpr int NC  = (G == 0 || G == 3) ? 1 : 3;  // output comps per bh
  constexpr int NF2 = (G == 0 || G == 2) ? 1 : 3;  // f2 rows kept in regs
  constexpr int NH  = (G == 0 || G == 1) ? 1 : 3;  // f1 comps (h scalars)
  constexpr int NCM = (G <= 1) ? 1 : 3;            // f1 comps staged in LDS
  constexpr int RB  = (G == 0) ? 0 : (G == 1) ? 128 : (G == 2) ? 512 : (G == 3) ? 896 : 1024;

  const int tid = threadIdx.x;
  const int lane = tid & 63, w = tid >> 6, l16 = lane & 15, quad = lane >> 4;
  const int tq = tid & 15, kp = tid >> 4;
  const int x = c >> (csh - 6);
  const int nsub = 1 << (7 - csh);

  int bidx[2];
  bidx[0] = w * 32 + l16;
  bidx[1] = w * 32 + 16 + l16;

  float hsx[2];
  hsx[0] = hsT[x * 128 + bidx[0]];
  hsx[1] = hsT[x * 128 + bidx[1]];

  // f2 fragments: [bh][comp][v-half], 8 bf16 each at v = h*32 + quad*8 + j
  v8s fr2[2][NF2][2];
#pragma unroll
  for (int bh = 0; bh < 2; ++bh)
#pragma unroll
    for (int m = 0; m < NF2; ++m)
#pragma unroll
      for (int h = 0; h < 2; ++h)
        fr2[bh][m][h] = *(const v8s*)(f2g + m * 8192 + bidx[bh] * 64 + h * 32 + quad * 8);

  v4f acc[2][NC][4];
#pragma unroll
  for (int bh = 0; bh < 2; ++bh)
#pragma unroll
    for (int cc = 0; cc < NC; ++cc)
#pragma unroll
      for (int nf = 0; nf < 4; ++nf) acc[bh][cc][nf] = (v4f){0.f, 0.f, 0.f, 0.f};

  const int swz_w = (tq & 3) << 2;           // write swizzle on k-dword index (bits 2-3)
  const int swz_r = ((l16 >> 2) & 3) << 2;   // matching read swizzle ((n>>2)&3)<<2

  float h[2][NH];

  for (int sub = 0; sub < nsub; ++sub) {
    const int kb = (c << (18 - csh)) + (sub << 11);  // k-base, 2048 k's per sub
    const int u0 = (kb >> 6) & 63;
    __syncthreads();  // prior sub's LDS reads done (no-op cost on first sub)
    // stage f1 slice [NCM][128][u0..u0+32) into ldsF1 [cm][b][40-padded]
    {
      const int nchk = NCM * 512;  // v8s chunks of 8 bf16
      for (int i = tid; i < nchk; i += 256) {
        const int uu8 = i & 3, b = (i >> 2) & 127, cm = i >> 9;
        *(v8s*)&ldsF1[(cm * 128 + b) * 40 + uu8 * 8] =
            *(const v8s*)(f1g + cm * 8192 + b * 64 + u0 + uu8 * 8);
      }
    }

    // B staging helpers: thread loads rows (2kp,2kp+1), cols 4tq..4tq+3 (coalesced 256B/16 lanes)
    auto gload = [&](int kk, float4& r0, float4& r1) {
      const float* s = P + (size_t)(kb + kk * 32 + 2 * kp) * 64 + 4 * tq;
      r0 = *(const float4*)s;
      r1 = *(const float4*)(s + 64);
    };
    auto bwrite = [&](int buf, const float4& r0, const float4& r1) {
      unsigned* dst = ldsB32 + (size_t)(buf * 64 + 4 * tq) * 20 + (kp ^ swz_w);
      dst[0]  = (unsigned)f2bf_rn(r0.x) | ((unsigned)f2bf_rn(r1.x) << 16);
      dst[20] = (unsigned)f2bf_rn(r0.y) | ((unsigned)f2bf_rn(r1.y) << 16);
      dst[40] = (unsigned)f2bf_rn(r0.z) | ((unsigned)f2bf_rn(r1.z) << 16);
      dst[60] = (unsigned)f2bf_rn(r0.w) | ((unsigned)f2bf_rn(r1.w) << 16);
    };

    // prologue: fill buf0, prefetch step 1
    float4 pa0, pa1;
    gload(0, pa0, pa1);
    bwrite(0, pa0, pa1);
    gload(1, pa0, pa1);
    __syncthreads();  // f1 slice + buf0 visible

#pragma unroll 2
    for (int kk = 0; kk < 64; ++kk) {
      const int buf = kk & 1;
      const int vh = kk & 1;  // v-half of this step
      // B fragments for this step (read current buffer first)
      v8s bfr[4];
#pragma unroll
      for (int nf = 0; nf < 4; ++nf)
        bfr[nf] = *(const v8s*)&ldsB32[(size_t)(buf * 64 + nf * 16 + l16) * 20 + ((quad * 4) ^ swz_r)];
      // u changed every 2 steps: refresh h scalars from LDS f1 slice
      if (vh == 0) {
        const int uu = kk >> 1;
#pragma unroll
        for (int bh = 0; bh < 2; ++bh)
#pragma unroll
          for (int m = 0; m < NH; ++m)
            h[bh][m] = hsx[bh] * bf2f(ldsF1[m * 5120 + bidx[bh] * 40 + uu]);
      }
      // pipeline: write next buffer, prefetch step kk+2
      if (kk < 63) bwrite(buf ^ 1, pa0, pa1);
      if (kk < 62) gload(kk + 2, pa0, pa1);
      // A fragments + MFMA
#pragma unroll
      for (int bh = 0; bh < 2; ++bh) {
#pragma unroll
        for (int cc = 0; cc < NC; ++cc) {
          v8s af;
#pragma unroll
          for (int j = 0; j < 8; ++j) {
            float p;
            if constexpr (G == 0)
              p = h[bh][0] * bf2f((unsigned short)fr2[bh][0][vh][j]);
            else if constexpr (G == 1)
              p = h[bh][0] * bf2f((unsigned short)fr2[bh][cc][vh][j]);
            else if constexpr (G == 2)
              p = h[bh][cc] * bf2f((unsigned short)fr2[bh][0][vh][j]);
            else if constexpr (G == 3)
              p = h[bh][0] * bf2f((unsigned short)fr2[bh][0][vh][j])
                + h[bh][1] * bf2f((unsigned short)fr2[bh][1][vh][j])
                + h[bh][2] * bf2f((unsigned short)fr2[bh][2][vh][j]);
            else {  // G == 4: eps-antisymmetric pair, comps (cc+1)%3, (cc+2)%3
              const int i1 = (cc + 1) % 3, j2 = (cc + 2) % 3;
              p = h[bh][i1] * bf2f((unsigned short)fr2[bh][j2][vh][j])
                - h[bh][j2] * bf2f((unsigned short)fr2[bh][i1][vh][j]);
            }
            af[j] = (short)(__float_as_uint(p) >> 16);  // truncating bf16 (unbiased noise in sum)
          }
#pragma unroll
          for (int nf = 0; nf < 4; ++nf)
            acc[bh][cc][nf] = __builtin_amdgcn_mfma_f32_16x16x32_bf16(af, bfr[nf], acc[bh][cc][nf], 0, 0, 0);
        }
      }
      __syncthreads();  // one barrier per K-step
    }
  }

  // epilogue: C/D layout col=l16, row=quad*4+r ; disjoint per-chunk partials
#pragma unroll
  for (int bh = 0; bh < 2; ++bh)
#pragma unroll
    for (int cc = 0; cc < NC; ++cc)
#pragma unroll
      for (int nf = 0; nf < 4; ++nf)
#pragma unroll
        for (int r = 0; r < 4; ++r) {
          const int row = RB + cc * 128 + w * 32 + bh * 16 + quad * 4 + r;
          partial[((size_t)c * 1408 + row) * 64 + nf * 16 + l16] = acc[bh][cc][nf][r];
        }
}

__global__ __launch_bounds__(256, 2) void tp_gemm(
    const float* __restrict__ P0, const float* __restrict__ P1, const float* __restrict__ P2,
    const float* __restrict__ P3, const float* __restrict__ P4,
    const unsigned short* __restrict__ s1c, const unsigned short* __restrict__ v1c,
    const unsigned short* __restrict__ s2c, const unsigned short* __restrict__ v2c,
    const float* __restrict__ hsT, float* __restrict__ partial, int csh)
{
  __shared__ __align__(16) unsigned ldsB32[2 * 64 * 20];        // double-buffered B tile, swizzled
  __shared__ __align__(16) unsigned short ldsF1[3 * 128 * 40];  // f1 slice [comp][b][u], padded
  const int g = blockIdx.x >> csh;
  const int c = blockIdx.x & ((1 << csh) - 1);
  switch (g) {
    case 0: gemm_body<0>(P0, s1c, s2c, hsT, partial, c, csh, ldsF1, ldsB32); break;
    case 1: gemm_body<1>(P1, s1c, v2c, hsT, partial, c, csh, ldsF1, ldsB32); break;
    case 2: gemm_body<2>(P2, v1c, s2c, hsT, partial, c, csh, ldsF1, ldsB32); break;
    case 3: gemm_body<3>(P3, v1c, v2c, hsT, partial, c, csh, ldsF1, ldsB32); break;
    default: gemm_body<4>(P4, v1c, v2c, hsT, partial, c, csh, ldsF1, ldsB32); break;
  }
}

// ---------------- finalize: sum K-chunk partials, assemble output ----------------
__global__ __launch_bounds__(448) void k_fin(const float* __restrict__ partial, float* __restrict__ out, int nch)
{
  const int b = blockIdx.x, i = threadIdx.x;
  int w, rA, rB;
  if (i < 64)       { w = i; rA = b; rB = 896 + b; }
  else if (i < 256) { const int t = i - 64;  w = t / 3; const int j = t - 3 * w; rA = 128 + j * 128 + b; rB = 512 + j * 128 + b; }
  else              { const int t = i - 256; w = t / 3; const int k = t - 3 * w; rA = 1024 + k * 128 + b; rB = rA; }
  const float* pA = partial + (size_t)rA * 64 + w;
  const float* pB = partial + (size_t)rB * 64 + w;
  float sA = 0.f, sB = 0.f;
#pragma unroll 4
  for (int cc = 0; cc < nch; ++cc) {
    sA += pA[(size_t)cc * 90112];
    sB += pB[(size_t)cc * 90112];
  }
  const float A01 = 0.011048543f;            // 1/sqrt(2*64*64)
  const float sc = 0.015625f * 0.70710678f;  // ALPHA_2 * INV_SQ2
  float o;
  if (i < 64)       o = A01 * (sA + 0.57735027f * sB);  // t0 + INV_SQ3*t3
  else if (i < 256) o = A01 * (sA + sB);                // t1 + t2
  else              o = sc * sA;                        // eps-combined t4
  out[b * 448 + i] = o;
}

extern "C" void kernel_launch(void* const* d_in, const int* in_sizes, int n_in,
                              void* d_out, int out_size, void* d_ws, size_t ws_size,
                              hipStream_t stream)
{
  const float* emb = (const float*)d_in[0];
  const float* x1  = (const float*)d_in[1];
  const float* x2  = (const float*)d_in[2];
  const float* W0  = (const float*)d_in[3];
  const float* W1  = (const float*)d_in[4];
  const float* W2  = (const float*)d_in[5];
  const float* P0  = (const float*)d_in[6];
  const float* P1  = (const float*)d_in[7];
  const float* P2  = (const float*)d_in[8];
  const float* P3  = (const float*)d_in[9];
  const float* P4  = (const float*)d_in[10];
  float* out = (float*)d_out;
  char* ws = (char*)d_ws;

  // persistent region (live during tp_gemm): [0, 163840)
  float* hsT = (float*)ws;                                // 32768 B
  unsigned short* s1c = (unsigned short*)(ws + 32768);    // 16384 B
  unsigned short* v1c = (unsigned short*)(ws + 49152);    // 49152 B
  unsigned short* s2c = (unsigned short*)(ws + 98304);    // 16384 B
  unsigned short* v2c = (unsigned short*)(ws + 114688);   // 49152 B
  // MLP activations alias the partial buffer (dead before tp_gemm runs)
  float* act1 = (float*)(ws + 163840);                    // 131072 B
  float* act2 = (float*)(ws + 294912);                    // 131072 B
  float* partial = (float*)(ws + 163840);                 // nch * 1408 * 64 * 4 B

  // 128 K-chunks (csh=7) needs 163840 + 46137344 B of ws; else 64 chunks (23.2 MB)
  const int csh = (ws_size >= (size_t)163840 + ((size_t)360448 << 7)) ? 7 : 6;

  k_mlp1<<<144, 256, 0, stream>>>(emb, W0, x1, x2, act1, s1c, v1c, s2c, v2c);
  k_mlp2<<<128, 256, 0, stream>>>(act1, W1, act2);
  k_mlp3<<<32, 256, 0, stream>>>(act2, W2, hsT);
  tp_gemm<<<5 << csh, 256, 0, stream>>>(P0, P1, P2, P3, P4, s1c, v1c, s2c, v2c, hsT, partial, csh);
  k_fin<<<128, 448, 0, stream>>>(partial, out, 1 << csh);
}